// Round 3
// baseline (582.785 us; speedup 1.0000x reference)
//
#include <hip/hip_runtime.h>

#define KK 5
#define NB 4
#define NC 64
#define NH 128
#define NW 128
#define HW (NH * NW)         // 16384
#define CHW (NC * HW)        // 1,048,576 elements (4 MB) — stride between K^2 slices
#define RPB 16               // output rows per block
#define LROWS (RPB + 4)      // 20 = 16 rows + 2 halo top + 2 halo bottom
#define LW 132               // 128 + 2 halo each side

typedef float vfloat4 __attribute__((ext_vector_type(4)));

// Block: 256 threads = 16 w-groups (x8 pixels) × 16 rows; covers one (b,c) strip of 16 rows.
// Grid: B*C*(H/16) = 4*64*8 = 2048 blocks.
// out[b,c,h,w] = sum_{i,j} core[b, i*5+j, c, h, w] * data_pad[b, c, h+i-2, w+j-2]
__global__ __launch_bounds__(256, 4) void kconv_kernel(const float* __restrict__ data,
                                                       const float* __restrict__ core,
                                                       float* __restrict__ out) {
    __shared__ float sdata[LROWS][LW];   // 20*132*4 = 10560 B

    const int tid = threadIdx.x;
    const int blk = blockIdx.x;
    const int hblk = blk & (NH / RPB - 1);       // 0..7
    const int c    = (blk >> 3) & (NC - 1);      // 0..63
    const int b    = blk >> 9;                   // 0..3
    const int h0   = hblk * RPB;

    const float* dbase = data + (size_t)(b * NC + c) * HW;

    // Cooperative stage of the 20x132 data window (global rows h0-2..h0+17, cols -2..129).
    for (int idx = tid; idx < LROWS * LW; idx += 256) {
        int r   = idx / LW;
        int col = idx - r * LW;
        int gh  = h0 + r - 2;
        int gw  = col - 2;
        float v = 0.f;
        if (gh >= 0 && gh < NH && gw >= 0 && gw < NW)
            v = dbase[gh * NW + gw];
        sdata[r][col] = v;
    }
    __syncthreads();

    const int w8    = tid & 15;          // 0..15  (8-pixel group)
    const int hr    = tid >> 4;          // 0..15
    const int h     = h0 + hr;
    const int wbase = w8 << 3;           // multiple of 8

    // core layout: [B, 25, C, H, W] -> ((b*25 + k)*C + c)*HW + h*W + w
    const float* cbase = core + (size_t)b * (KK * KK) * (size_t)CHW
                              + (size_t)c * HW + (size_t)(h * NW + wbase);

    vfloat4 acc0 = {0.f, 0.f, 0.f, 0.f};
    vfloat4 acc1 = {0.f, 0.f, 0.f, 0.f};

    #pragma unroll
    for (int i = 0; i < KK; ++i) {
        // global row h+i-2 -> LDS row (hr+i); padded col: global (wbase-2) -> LDS wbase
        const float* lrow = &sdata[hr + i][wbase];
        vfloat4 d0 = *reinterpret_cast<const vfloat4*>(lrow);       // g cols wbase-2 .. +1
        vfloat4 d1 = *reinterpret_cast<const vfloat4*>(lrow + 4);   // g cols wbase+2 .. +5
        vfloat4 d2 = *reinterpret_cast<const vfloat4*>(lrow + 8);   // g cols wbase+6 .. +9
        float d[12] = {d0.x, d0.y, d0.z, d0.w, d1.x, d1.y, d1.z, d1.w,
                       d2.x, d2.y, d2.z, d2.w};
        #pragma unroll
        for (int j = 0; j < KK; ++j) {
            const int k = i * KK + j;
            const float* ckp = cbase + (size_t)k * CHW;
            vfloat4 ck0 = __builtin_nontemporal_load(reinterpret_cast<const vfloat4*>(ckp));
            vfloat4 ck1 = __builtin_nontemporal_load(reinterpret_cast<const vfloat4*>(ckp + 4));
            acc0.x = fmaf(ck0.x, d[j + 0], acc0.x);
            acc0.y = fmaf(ck0.y, d[j + 1], acc0.y);
            acc0.z = fmaf(ck0.z, d[j + 2], acc0.z);
            acc0.w = fmaf(ck0.w, d[j + 3], acc0.w);
            acc1.x = fmaf(ck1.x, d[j + 4], acc1.x);
            acc1.y = fmaf(ck1.y, d[j + 5], acc1.y);
            acc1.z = fmaf(ck1.z, d[j + 6], acc1.z);
            acc1.w = fmaf(ck1.w, d[j + 7], acc1.w);
        }
    }

    float* op = out + (size_t)(b * NC + c) * HW + (size_t)(h * NW + wbase);
    __builtin_nontemporal_store(acc0, reinterpret_cast<vfloat4*>(op));
    __builtin_nontemporal_store(acc1, reinterpret_cast<vfloat4*>(op + 4));
}

extern "C" void kernel_launch(void* const* d_in, const int* in_sizes, int n_in,
                              void* d_out, int out_size, void* d_ws, size_t ws_size,
                              hipStream_t stream) {
    const float* data = (const float*)d_in[0];   // [4, 64, 128, 128]
    const float* core = (const float*)d_in[1];   // [4, 25*64, 128, 128]
    float* out = (float*)d_out;                  // [4, 64, 128, 128]

    dim3 block(256);
    dim3 grid(NB * NC * (NH / RPB));             // 2048 blocks
    kconv_kernel<<<grid, block, 0, stream>>>(data, core, out);
}